// Round 11
// baseline (323.079 us; speedup 1.0000x reference)
//
#include <hip/hip_runtime.h>
#include <hip/hip_bf16.h>

#define N_PTS 8192
#define KNN 8

typedef __attribute__((ext_vector_type(8))) short short8;
typedef __attribute__((ext_vector_type(4))) float float4v;
typedef unsigned long long u64;

// f32 -> bf16 round-to-nearest-even (finite inputs only)
static __device__ __forceinline__ short f2bf(float f) {
    unsigned u = __float_as_uint(f);
    unsigned r = (u + 0x7FFFu + ((u >> 16) & 1u)) >> 16;
    return (short)r;
}
static __device__ __forceinline__ float bf2f(short s) {
    return __uint_as_float(((unsigned)(unsigned short)s) << 16);
}

static __device__ __forceinline__ void ins8(u64* best, u64 x) {
#pragma unroll
    for (int j = 0; j < 8; ++j) {
        const u64 lo = x < best[j] ? x : best[j];
        const u64 hi = x < best[j] ? best[j] : x;
        best[j] = lo; x = hi;
    }
}

// ---------------------------------------------------------------------------
// FUSED knn_partial + q/kv GEMM in ONE dispatch (2560 blocks, 2:3 interleave).
// Rationale [m114]: MFMA-pipe waves and VALU-pipe waves on the same CU
// co-schedule (time ~ max, not sum). knn is ~90% VALU / 0% MFMA; the GEMM is
// MFMA-bound. Independent data: knn reads pos -> partial; gemm reads
// xb/wqkvt -> qall/kvall (partial no longer aliases kvall!).
// Branch is block-uniform; LDS = max(40.96K knn, 20.5K gemm) -> 3 blocks/CU,
// same residency knn measured alone (occ 32.5%).
//
// knn part: EXACT round-5/-10 algorithm (measured 81 us, VALUBusy 88%):
// one query/thread, 16 partitions x 512 cand, SoA xyz LDS broadcasts,
// branchless 32 rotating bucket minima on exact-difference d2, threshold =
// 8th smallest bucket min, collect <= t (cap 16, exact-rescan fallback),
// exact top-8 over (d2bits<<32|idx) u64 keys.
//
// gemm part: xb[16384,256] x wqkvt[1536,256]^T, 128x128 tile, BK=32,
// 4 waves 2x2, 16x16x32 MFMA (layouts per m89/m91, correct rounds 4-10);
// cols [0,512) -> qall (stride 512), [512,1536) -> kvall (stride 1024).
// ---------------------------------------------------------------------------
__global__ __launch_bounds__(256) void fused_knn_qkv(const float* __restrict__ pos,
                                                     u64* __restrict__ partial,
                                                     const short* __restrict__ A,
                                                     const short* __restrict__ Bt,
                                                     short* __restrict__ qall,
                                                     short* __restrict__ kvall)
{
    __shared__ char smem[40960];

    const int tid = threadIdx.x;
    const int g5 = blockIdx.x / 5;
    const int r5 = blockIdx.x % 5;

    if (r5 < 2) {
        // ================= KNN block (1024 total) =========================
        const int kb = g5 * 2 + r5;             // knn block id 0..1023
        float* sx = (float*)smem;               // 512 f32
        float* sy = sx + 512;
        float* sz = sy + 512;
        u64* buf = (u64*)(smem + 6144);         // [256][17]

        const int p   = kb & 15;
        const int qg  = kb >> 4;
        const int batch = qg >> 5;
        const int q_in_b = (qg & 31) * 256 + tid;
        const float* bpos = pos + (long)batch * N_PTS * 3;

        if (tid < 128) {
            const float* src = bpos + (p * 512 + tid * 4) * 3;
            const float4 f0 = *(const float4*)(src);
            const float4 f1 = *(const float4*)(src + 4);
            const float4 f2 = *(const float4*)(src + 8);
            const int c0 = tid * 4;
            *(float4*)&sx[c0] = make_float4(f0.x, f0.w, f1.z, f2.y);
            *(float4*)&sy[c0] = make_float4(f0.y, f1.x, f1.w, f2.z);
            *(float4*)&sz[c0] = make_float4(f0.z, f1.y, f2.x, f2.w);
        }
        __syncthreads();

        const float qx = bpos[q_in_b * 3 + 0];
        const float qy = bpos[q_in_b * 3 + 1];
        const float qz = bpos[q_in_b * 3 + 2];

        const float4* vx = (const float4*)sx;
        const float4* vy = (const float4*)sy;
        const float4* vz = (const float4*)sz;

        float bmin[32];
#pragma unroll
        for (int j = 0; j < 32; ++j) bmin[j] = 3.0e38f;

        for (int base = 0; base < 128; base += 8) {
#pragma unroll
            for (int g = 0; g < 8; ++g) {
                const float4 cx = vx[base + g];
                const float4 cy = vy[base + g];
                const float4 cz = vz[base + g];
                { const float dx = cx.x - qx, dy = cy.x - qy, dz = cz.x - qz;
                  bmin[g*4+0] = fminf(bmin[g*4+0], fmaf(dx, dx, fmaf(dy, dy, dz*dz))); }
                { const float dx = cx.y - qx, dy = cy.y - qy, dz = cz.y - qz;
                  bmin[g*4+1] = fminf(bmin[g*4+1], fmaf(dx, dx, fmaf(dy, dy, dz*dz))); }
                { const float dx = cx.z - qx, dy = cy.z - qy, dz = cz.z - qz;
                  bmin[g*4+2] = fminf(bmin[g*4+2], fmaf(dx, dx, fmaf(dy, dy, dz*dz))); }
                { const float dx = cx.w - qx, dy = cy.w - qy, dz = cz.w - qz;
                  bmin[g*4+3] = fminf(bmin[g*4+3], fmaf(dx, dx, fmaf(dy, dy, dz*dz))); }
            }
        }

        float t8[8];
#pragma unroll
        for (int j = 0; j < 8; ++j) t8[j] = 3.0e38f;
#pragma unroll
        for (int i = 0; i < 32; ++i) {
            float x = bmin[i];
#pragma unroll
            for (int j = 0; j < 8; ++j) {
                const float lo = fminf(t8[j], x);
                const float hi = fmaxf(t8[j], x);
                t8[j] = lo; x = hi;
            }
        }
        const float t = t8[7];

        int cnt = 0;
        for (int base = 0; base < 128; ++base) {
            const float4 cx = vx[base];
            const float4 cy = vy[base];
            const float4 cz = vz[base];
#pragma unroll
            for (int j = 0; j < 4; ++j) {
                const float ccx = j == 0 ? cx.x : j == 1 ? cx.y : j == 2 ? cx.z : cx.w;
                const float ccy = j == 0 ? cy.x : j == 1 ? cy.y : j == 2 ? cy.z : cy.w;
                const float ccz = j == 0 ? cz.x : j == 1 ? cz.y : j == 2 ? cz.z : cz.w;
                const float dx = ccx - qx, dy = ccy - qy, dz = ccz - qz;
                const float d2 = fmaf(dx, dx, fmaf(dy, dy, dz * dz));
                if (d2 <= t) {
                    buf[tid * 17 + (cnt < 16 ? cnt : 16)] =
                        ((u64)__float_as_uint(d2) << 32)
                        | (unsigned)(p * 512 + base * 4 + j);
                    ++cnt;
                }
            }
        }

        u64 best[8];
#pragma unroll
        for (int j = 0; j < 8; ++j) best[j] = ~0ULL;

        if (cnt <= 16) {
            for (int u = 0; u < cnt; ++u) ins8(best, buf[tid * 17 + u]);
        } else {
            for (int i = 0; i < 512; ++i) {     // statistically-never fallback
                const float dx = sx[i] - qx, dy = sy[i] - qy, dz = sz[i] - qz;
                const float d2 = fmaf(dx, dx, fmaf(dy, dy, dz * dz));
                u64 x = ((u64)__float_as_uint(d2) << 32) | (unsigned)(p * 512 + i);
                if (x < best[7]) ins8(best, x);
            }
        }

        const long qglob = (long)batch * N_PTS + q_in_b;
#pragma unroll
        for (int j = 0; j < 8; ++j)
            partial[(long)(p * 8 + j) * 16384 + qglob] = best[j];   // coalesced

    } else {
        // ================= GEMM block (1536 total) ========================
        const int id = g5 * 3 + (r5 - 2);       // 0..1535
        const int bx = id % 12;
        const int by = id / 12;

        short (*As)[40] = (short(*)[40])smem;             // 128x40
        short (*Bs)[40] = (short(*)[40])(smem + 10240);   // 128x40

        const int lane = tid & 63;
        const int wv   = tid >> 6;
        const int quad = lane >> 4;
        const int l15  = lane & 15;
        const int m0 = by * 128;
        const int n0 = bx * 128;
        const int mh = (wv & 1) * 64, nh = (wv >> 1) * 64;

        const int srow  = tid >> 1;
        const int shalf = (tid & 1) * 16;
        const int Kd = 256;

        float4v acc[4][4];
#pragma unroll
        for (int i = 0; i < 4; ++i)
#pragma unroll
            for (int j = 0; j < 4; ++j) acc[i][j] = (float4v)(0.f);

        for (int k0 = 0; k0 < Kd; k0 += 32) {
            const short8* asrc = (const short8*)(A + (long)(m0 + srow) * Kd + k0 + shalf);
            const short8* bsrc = (const short8*)(Bt + (long)(n0 + srow) * Kd + k0 + shalf);
            *(short8*)&As[srow][shalf]     = asrc[0];
            *(short8*)&As[srow][shalf + 8] = asrc[1];
            *(short8*)&Bs[srow][shalf]     = bsrc[0];
            *(short8*)&Bs[srow][shalf + 8] = bsrc[1];
            __syncthreads();

            short8 af[4], bfv[4];
#pragma unroll
            for (int i = 0; i < 4; ++i)
                af[i] = *(const short8*)&As[mh + i * 16 + l15][quad * 8];
#pragma unroll
            for (int j = 0; j < 4; ++j)
                bfv[j] = *(const short8*)&Bs[nh + j * 16 + l15][quad * 8];
#pragma unroll
            for (int i = 0; i < 4; ++i)
#pragma unroll
                for (int j = 0; j < 4; ++j)
                    acc[i][j] = __builtin_amdgcn_mfma_f32_16x16x32_bf16(af[i], bfv[j], acc[i][j], 0, 0, 0);
            __syncthreads();
        }

        short* Cb;
        int stride, cb;
        if (n0 < 512) { Cb = qall;  stride = 512;  cb = n0; }
        else          { Cb = kvall; stride = 1024; cb = n0 - 512; }

#pragma unroll
        for (int i = 0; i < 4; ++i)
#pragma unroll
            for (int j = 0; j < 4; ++j) {
                const int col = cb + nh + j * 16 + l15;
#pragma unroll
                for (int r = 0; r < 4; ++r) {
                    const int row = m0 + mh + i * 16 + quad * 4 + r;
                    Cb[(long)row * stride + col] = f2bf(acc[i][j][r]);
                }
            }
    }
}

// ---------------------------------------------------------------------------
// KNN stage 2: merge 16 partitions x 8 slots per query (slot-major, coalesced).
// ---------------------------------------------------------------------------
__global__ __launch_bounds__(256) void knn_merge(const u64* __restrict__ partial,
                                                 int* __restrict__ idxo)
{
    const int q = blockIdx.x * 256 + threadIdx.x;
    u64 best[8];
#pragma unroll
    for (int j = 0; j < 8; ++j) best[j] = ~0ULL;
    for (int s = 0; s < 128; ++s) {
        u64 x = partial[(long)s * 16384 + q];
        if (x < best[7]) ins8(best, x);
    }
#pragma unroll
    for (int j = 0; j < 8; ++j)
        idxo[(long)q * 8 + j] = (int)(best[j] & 0xFFFFFFFFu);
}

// ---------------------------------------------------------------------------
// All f32->bf16 conversions in ONE dispatch (as round 10).
// ---------------------------------------------------------------------------
__global__ __launch_bounds__(256) void conv_all(const float* __restrict__ x,
                                                const float* __restrict__ Wq,
                                                const float* __restrict__ Wkv,
                                                const float* __restrict__ Wout,
                                                short* __restrict__ xb,
                                                short* __restrict__ wqkvt,
                                                short* __restrict__ woutt)
{
    const int bid = blockIdx.x;
    const int tid = threadIdx.x;
    if (bid < 2048) {
        const int i = bid * 256 + tid;
        const float4 a = ((const float4*)x)[i * 2];
        const float4 b = ((const float4*)x)[i * 2 + 1];
        short8 w = {f2bf(a.x), f2bf(a.y), f2bf(a.z), f2bf(a.w),
                    f2bf(b.x), f2bf(b.y), f2bf(b.z), f2bf(b.w)};
        ((short8*)xb)[i] = w;
    } else if (bid < 2560) {
        const int o = (bid - 2048) * 256 + tid;      // n*256+k, n<512
        const int n = o >> 8, k = o & 255;
        wqkvt[o] = f2bf(Wq[(long)k * 512 + n]);
    } else if (bid < 3584) {
        const int o = (bid - 2560) * 256 + tid;      // n*256+k, n<1024
        const int n = o >> 8, k = o & 255;
        wqkvt[131072 + o] = f2bf(Wkv[(long)k * 1024 + n]);
    } else {
        const int o = (bid - 3584) * 256 + tid;      // n*512+k, n<256
        const int n = o >> 9, k = o & 511;
        woutt[o] = f2bf(Wout[(long)k * 256 + n]);
    }
}

// ---------------------------------------------------------------------------
// Out-projection bf16 MFMA GEMM: C f32 = A[M,512] x Bt[256,512]^T + bias.
// ---------------------------------------------------------------------------
__global__ __launch_bounds__(256) void gemm_out(const short* __restrict__ A,
                                                const short* __restrict__ Bt,
                                                const float* __restrict__ bias,
                                                float* __restrict__ C,
                                                int N, int Kd)
{
    __shared__ short As[128][40];
    __shared__ short Bs[128][40];

    const int tid  = threadIdx.x;
    const int lane = tid & 63;
    const int wv   = tid >> 6;
    const int quad = lane >> 4;
    const int l15  = lane & 15;
    const int m0 = blockIdx.y * 128;
    const int n0 = blockIdx.x * 128;
    const int mh = (wv & 1) * 64, nh = (wv >> 1) * 64;

    const int srow  = tid >> 1;
    const int shalf = (tid & 1) * 16;

    float4v acc[4][4];
#pragma unroll
    for (int i = 0; i < 4; ++i)
#pragma unroll
        for (int j = 0; j < 4; ++j) acc[i][j] = (float4v)(0.f);

    for (int k0 = 0; k0 < Kd; k0 += 32) {
        const short8* asrc = (const short8*)(A + (long)(m0 + srow) * Kd + k0 + shalf);
        const short8* bsrc = (const short8*)(Bt + (long)(n0 + srow) * Kd + k0 + shalf);
        *(short8*)&As[srow][shalf]     = asrc[0];
        *(short8*)&As[srow][shalf + 8] = asrc[1];
        *(short8*)&Bs[srow][shalf]     = bsrc[0];
        *(short8*)&Bs[srow][shalf + 8] = bsrc[1];
        __syncthreads();

        short8 af[4], bfv[4];
#pragma unroll
        for (int i = 0; i < 4; ++i)
            af[i] = *(const short8*)&As[mh + i * 16 + l15][quad * 8];
#pragma unroll
        for (int j = 0; j < 4; ++j)
            bfv[j] = *(const short8*)&Bs[nh + j * 16 + l15][quad * 8];
#pragma unroll
        for (int i = 0; i < 4; ++i)
#pragma unroll
            for (int j = 0; j < 4; ++j)
                acc[i][j] = __builtin_amdgcn_mfma_f32_16x16x32_bf16(af[i], bfv[j], acc[i][j], 0, 0, 0);
        __syncthreads();
    }

#pragma unroll
    for (int i = 0; i < 4; ++i)
#pragma unroll
        for (int j = 0; j < 4; ++j) {
            const int col = n0 + nh + j * 16 + l15;
            const float bb = bias[col];
#pragma unroll
            for (int r = 0; r < 4; ++r) {
                const int row = m0 + mh + i * 16 + quad * 4 + r;
                C[(long)row * N + col] = acc[i][j][r] + bb;
            }
        }
}

// ---------------------------------------------------------------------------
// Fused KNN attention, bf16 storage / f32 math (unchanged since round 5).
// ---------------------------------------------------------------------------
__global__ __launch_bounds__(256) void attn_kernel(const short* qall,
                                                   const short* __restrict__ kvall,
                                                   const int* __restrict__ idxp,
                                                   short* outp)
{
    __shared__ float attn_s[4][8][8];
    const int wave = threadIdx.x >> 6;
    const int lane = threadIdx.x & 63;
    const int g = blockIdx.x * 4 + wave;
    const int b = g >> 13;
    const int* myidx = idxp + (long)g * 8;

    {
        const int h = lane >> 3;
        const int k = lane & 7;
        const int j = myidx[k];
        const short8* qrow = (const short8*)(qall + (long)g * 512 + h * 64);
        const short8* krow = (const short8*)(kvall + ((long)(b * N_PTS + j)) * 1024 + h * 64);

        float dot = 0.f;
#pragma unroll
        for (int c = 0; c < 8; ++c) {
            const short8 qv = qrow[c];
            const short8 kv = krow[c];
#pragma unroll
            for (int e = 0; e < 8; ++e)
                dot = fmaf(bf2f(qv[e]), bf2f(kv[e]), dot);
        }
        dot *= 0.125f;

        float m = dot;
#pragma unroll
        for (int off = 1; off < 8; off <<= 1)
            m = fmaxf(m, __shfl_xor(m, off, 8));
        const float e = __expf(dot - m);
        float ssum = e;
#pragma unroll
        for (int off = 1; off < 8; off <<= 1)
            ssum += __shfl_xor(ssum, off, 8);
        attn_s[wave][h][k] = e / ssum;
    }
    __syncthreads();                      // drains q reads before aliased writes

    const int d8 = lane * 8;
    const int h2 = lane >> 3;
    float o[8] = {0.f, 0.f, 0.f, 0.f, 0.f, 0.f, 0.f, 0.f};
#pragma unroll
    for (int kk = 0; kk < 8; ++kk) {
        const int jj = myidx[kk];
        const float w = attn_s[wave][h2][kk];
        const short8 v = *(const short8*)(kvall + ((long)(b * N_PTS + jj)) * 1024 + 512 + d8);
#pragma unroll
        for (int e = 0; e < 8; ++e)
            o[e] = fmaf(w, bf2f(v[e]), o[e]);
    }
    short8 ov = {f2bf(o[0]), f2bf(o[1]), f2bf(o[2]), f2bf(o[3]),
                 f2bf(o[4]), f2bf(o[5]), f2bf(o[6]), f2bf(o[7])};
    *(short8*)(outp + (long)g * 512 + d8) = ov;
}

// ---------------------------------------------------------------------------
extern "C" void kernel_launch(void* const* d_in, const int* in_sizes, int n_in,
                              void* d_out, int out_size, void* d_ws, size_t ws_size,
                              hipStream_t stream)
{
    const float* x    = (const float*)d_in[0];  // [2,8192,256]
    const float* pos  = (const float*)d_in[1];  // [2,8192,3]
    const float* Wq   = (const float*)d_in[2];  // [256,512]
    const float* Wkv  = (const float*)d_in[3];  // [256,1024]
    const float* Wout = (const float*)d_in[4];  // [512,256]
    const float* bout = (const float*)d_in[5];  // [256]
    float* out = (float*)d_out;                 // [2,8192,256] f32

    const int M = 16384;

    // workspace layout (partial now has its OWN slice -- it is written
    // concurrently with kvall inside the fused dispatch):
    char* ws = (char*)d_ws;
    int*   idxp  = (int*)ws;                          ws += 1 << 19;             // 512 KB
    short* qall  = (short*)ws;                        ws += (long)M * 512 * 2;   // 16 MB
    short* kvall = (short*)ws;                        ws += (long)M * 1024 * 2;  // 32 MB
    short* xb    = (short*)ws;                        ws += (long)M * 256 * 2;   // 8 MB
    short* wqkvt = (short*)ws;                        ws += 1536 * 256 * 2;      // 768 KB
    short* woutt = (short*)ws;                        ws += 256 * 512 * 2;       // 256 KB
    u64*  partial = (u64*)ws;                         ws += (long)128 * 16384 * 8; // 16 MB

    conv_all<<<4096, 256, 0, stream>>>(x, Wq, Wkv, Wout, xb, wqkvt, woutt);
    fused_knn_qkv<<<2560, 256, 0, stream>>>(pos, partial, xb, wqkvt, qall, kvall);
    knn_merge<<<64, 256, 0, stream>>>(partial, idxp);
    attn_kernel<<<M / 4, 256, 0, stream>>>(qall, kvall, idxp, qall);   // in-place
    gemm_out<<<dim3(2, 128), 256, 0, stream>>>(qall, woutt, bout, out, 256, 512);
}

// Round 12
// 301.122 us; speedup vs baseline: 1.0729x; 1.0729x over previous
//
#include <hip/hip_runtime.h>
#include <hip/hip_bf16.h>

#define N_PTS 8192
#define KNN 8

typedef __attribute__((ext_vector_type(8))) short short8;
typedef __attribute__((ext_vector_type(4))) float float4v;
typedef unsigned long long u64;

// f32 -> bf16 round-to-nearest-even (finite inputs only)
static __device__ __forceinline__ short f2bf(float f) {
    unsigned u = __float_as_uint(f);
    unsigned r = (u + 0x7FFFu + ((u >> 16) & 1u)) >> 16;
    return (short)r;
}
static __device__ __forceinline__ float bf2f(short s) {
    return __uint_as_float(((unsigned)(unsigned short)s) << 16);
}

static __device__ __forceinline__ void ins8(u64* best, u64 x) {
#pragma unroll
    for (int j = 0; j < 8; ++j) {
        const u64 lo = x < best[j] ? x : best[j];
        const u64 hi = x < best[j] ? best[j] : x;
        best[j] = lo; x = hi;
    }
}

// ---------------------------------------------------------------------------
// Dispatch 1: knn_partial (1024 blocks) + all f32->bf16 conversions (4096
// blocks), 1:4 interleave. FUSION RULE (learned r11): the partner of an
// LDS-heavy kernel must be LDS-FREE and short-lived, else it steals
// residency slots (r11: gemm partner at max-LDS slots stretched knn 81->132).
// conv uses zero LDS and ~10 us of pure VMEM -> knn keeps ~3 blocks/CU.
//
// knn part: EXACT round-5/-10 algorithm (81 us, VALUBusy 88%): one query per
// thread, 16 partitions x 512 cand, SoA xyz LDS broadcasts, branchless 32
// rotating bucket minima on exact-difference d2, threshold = 8th smallest
// bucket min, collect <= t (cap 16, exact-rescan fallback), exact top-8 over
// (d2bits<<32|idx) u64 keys.
// ---------------------------------------------------------------------------
__global__ __launch_bounds__(256) void fused_knn_conv(const float* __restrict__ pos,
                                                      u64* __restrict__ partial,
                                                      const float* __restrict__ x,
                                                      const float* __restrict__ Wq,
                                                      const float* __restrict__ Wkv,
                                                      const float* __restrict__ Wout,
                                                      short* __restrict__ xb,
                                                      short* __restrict__ wqkvt,
                                                      short* __restrict__ woutt)
{
    __shared__ char smem[40960];
    const int tid = threadIdx.x;
    const int g5 = blockIdx.x / 5;
    const int r5 = blockIdx.x % 5;

    if (r5 == 0) {
        // ================= KNN block (1024 total) =========================
        const int kb = g5;                       // 0..1023
        float* sx = (float*)smem;                // 512 f32
        float* sy = sx + 512;
        float* sz = sy + 512;
        u64* buf = (u64*)(smem + 6144);          // [256][17]

        const int p   = kb & 15;
        const int qg  = kb >> 4;
        const int batch = qg >> 5;
        const int q_in_b = (qg & 31) * 256 + tid;
        const float* bpos = pos + (long)batch * N_PTS * 3;

        if (tid < 128) {
            const float* src = bpos + (p * 512 + tid * 4) * 3;
            const float4 f0 = *(const float4*)(src);
            const float4 f1 = *(const float4*)(src + 4);
            const float4 f2 = *(const float4*)(src + 8);
            const int c0 = tid * 4;
            *(float4*)&sx[c0] = make_float4(f0.x, f0.w, f1.z, f2.y);
            *(float4*)&sy[c0] = make_float4(f0.y, f1.x, f1.w, f2.z);
            *(float4*)&sz[c0] = make_float4(f0.z, f1.y, f2.x, f2.w);
        }
        __syncthreads();

        const float qx = bpos[q_in_b * 3 + 0];
        const float qy = bpos[q_in_b * 3 + 1];
        const float qz = bpos[q_in_b * 3 + 2];

        const float4* vx = (const float4*)sx;
        const float4* vy = (const float4*)sy;
        const float4* vz = (const float4*)sz;

        float bmin[32];
#pragma unroll
        for (int j = 0; j < 32; ++j) bmin[j] = 3.0e38f;

        for (int base = 0; base < 128; base += 8) {
#pragma unroll
            for (int g = 0; g < 8; ++g) {
                const float4 cx = vx[base + g];
                const float4 cy = vy[base + g];
                const float4 cz = vz[base + g];
                { const float dx = cx.x - qx, dy = cy.x - qy, dz = cz.x - qz;
                  bmin[g*4+0] = fminf(bmin[g*4+0], fmaf(dx, dx, fmaf(dy, dy, dz*dz))); }
                { const float dx = cx.y - qx, dy = cy.y - qy, dz = cz.y - qz;
                  bmin[g*4+1] = fminf(bmin[g*4+1], fmaf(dx, dx, fmaf(dy, dy, dz*dz))); }
                { const float dx = cx.z - qx, dy = cy.z - qy, dz = cz.z - qz;
                  bmin[g*4+2] = fminf(bmin[g*4+2], fmaf(dx, dx, fmaf(dy, dy, dz*dz))); }
                { const float dx = cx.w - qx, dy = cy.w - qy, dz = cz.w - qz;
                  bmin[g*4+3] = fminf(bmin[g*4+3], fmaf(dx, dx, fmaf(dy, dy, dz*dz))); }
            }
        }

        float t8[8];
#pragma unroll
        for (int j = 0; j < 8; ++j) t8[j] = 3.0e38f;
#pragma unroll
        for (int i = 0; i < 32; ++i) {
            float x_ = bmin[i];
#pragma unroll
            for (int j = 0; j < 8; ++j) {
                const float lo = fminf(t8[j], x_);
                const float hi = fmaxf(t8[j], x_);
                t8[j] = lo; x_ = hi;
            }
        }
        const float t = t8[7];

        int cnt = 0;
        for (int base = 0; base < 128; ++base) {
            const float4 cx = vx[base];
            const float4 cy = vy[base];
            const float4 cz = vz[base];
#pragma unroll
            for (int j = 0; j < 4; ++j) {
                const float ccx = j == 0 ? cx.x : j == 1 ? cx.y : j == 2 ? cx.z : cx.w;
                const float ccy = j == 0 ? cy.x : j == 1 ? cy.y : j == 2 ? cy.z : cy.w;
                const float ccz = j == 0 ? cz.x : j == 1 ? cz.y : j == 2 ? cz.z : cz.w;
                const float dx = ccx - qx, dy = ccy - qy, dz = ccz - qz;
                const float d2 = fmaf(dx, dx, fmaf(dy, dy, dz * dz));
                if (d2 <= t) {
                    buf[tid * 17 + (cnt < 16 ? cnt : 16)] =
                        ((u64)__float_as_uint(d2) << 32)
                        | (unsigned)(p * 512 + base * 4 + j);
                    ++cnt;
                }
            }
        }

        u64 best[8];
#pragma unroll
        for (int j = 0; j < 8; ++j) best[j] = ~0ULL;

        if (cnt <= 16) {
            for (int u = 0; u < cnt; ++u) ins8(best, buf[tid * 17 + u]);
        } else {
            for (int i = 0; i < 512; ++i) {     // statistically-never fallback
                const float dx = sx[i] - qx, dy = sy[i] - qy, dz = sz[i] - qz;
                const float d2 = fmaf(dx, dx, fmaf(dy, dy, dz * dz));
                u64 x_ = ((u64)__float_as_uint(d2) << 32) | (unsigned)(p * 512 + i);
                if (x_ < best[7]) ins8(best, x_);
            }
        }

        const long qglob = (long)batch * N_PTS + q_in_b;
#pragma unroll
        for (int j = 0; j < 8; ++j)
            partial[(long)(p * 8 + j) * 16384 + qglob] = best[j];   // coalesced

    } else {
        // ================= conv block (4096 total, zero LDS) ==============
        const int bid = g5 * 4 + (r5 - 1);      // 0..4095
        if (bid < 2048) {
            const int i = bid * 256 + tid;
            const float4 a = ((const float4*)x)[i * 2];
            const float4 b = ((const float4*)x)[i * 2 + 1];
            short8 w = {f2bf(a.x), f2bf(a.y), f2bf(a.z), f2bf(a.w),
                        f2bf(b.x), f2bf(b.y), f2bf(b.z), f2bf(b.w)};
            ((short8*)xb)[i] = w;
        } else if (bid < 2560) {
            const int o = (bid - 2048) * 256 + tid;      // n*256+k, n<512
            const int n = o >> 8, k = o & 255;
            wqkvt[o] = f2bf(Wq[(long)k * 512 + n]);
        } else if (bid < 3584) {
            const int o = (bid - 2560) * 256 + tid;      // n*256+k, n<1024
            const int n = o >> 8, k = o & 255;
            wqkvt[131072 + o] = f2bf(Wkv[(long)k * 1024 + n]);
        } else {
            const int o = (bid - 3584) * 256 + tid;      // n*512+k, n<256
            const int n = o >> 9, k = o & 511;
            woutt[o] = f2bf(Wout[(long)k * 256 + n]);
        }
    }
}

// ---------------------------------------------------------------------------
// Dispatch 2: q/kv GEMM (1536 blocks) + knn_merge (first 64 blocks).
// merge uses zero LDS and standalone is a 1-wave/CU latency-bound straggler
// (~10-15 us); co-resident with the gemm flood it hides completely.
// gemm: xb[16384,256] x wqkvt[1536,256]^T, 128x128 tile, BK=32, 4 waves 2x2,
// 16x16x32 MFMA (layouts per m89/m91; correct rounds 4-11); cols [0,512) ->
// qall (stride 512), [512,1536) -> kvall (stride 1024).
// ---------------------------------------------------------------------------
__global__ __launch_bounds__(256) void fused_gemm_merge(const short* __restrict__ A,
                                                        const short* __restrict__ Bt,
                                                        short* __restrict__ qall,
                                                        short* __restrict__ kvall,
                                                        const u64* __restrict__ partial,
                                                        int* __restrict__ idxo)
{
    __shared__ short As[128][40];
    __shared__ short Bs[128][40];

    const int tid = threadIdx.x;

    if (blockIdx.x < 64) {
        // ================= merge block (zero LDS) =========================
        const int q = blockIdx.x * 256 + tid;
        u64 best[8];
#pragma unroll
        for (int j = 0; j < 8; ++j) best[j] = ~0ULL;
        for (int s = 0; s < 128; ++s) {
            u64 x = partial[(long)s * 16384 + q];
            if (x < best[7]) ins8(best, x);
        }
#pragma unroll
        for (int j = 0; j < 8; ++j)
            idxo[(long)q * 8 + j] = (int)(best[j] & 0xFFFFFFFFu);
        return;
    }

    // ================= GEMM block (1536 total) ============================
    const int id = blockIdx.x - 64;
    const int bx = id % 12;
    const int by = id / 12;

    const int lane = tid & 63;
    const int wv   = tid >> 6;
    const int quad = lane >> 4;
    const int l15  = lane & 15;
    const int m0 = by * 128;
    const int n0 = bx * 128;
    const int mh = (wv & 1) * 64, nh = (wv >> 1) * 64;

    const int srow  = tid >> 1;
    const int shalf = (tid & 1) * 16;
    const int Kd = 256;

    float4v acc[4][4];
#pragma unroll
    for (int i = 0; i < 4; ++i)
#pragma unroll
        for (int j = 0; j < 4; ++j) acc[i][j] = (float4v)(0.f);

    for (int k0 = 0; k0 < Kd; k0 += 32) {
        const short8* asrc = (const short8*)(A + (long)(m0 + srow) * Kd + k0 + shalf);
        const short8* bsrc = (const short8*)(Bt + (long)(n0 + srow) * Kd + k0 + shalf);
        *(short8*)&As[srow][shalf]     = asrc[0];
        *(short8*)&As[srow][shalf + 8] = asrc[1];
        *(short8*)&Bs[srow][shalf]     = bsrc[0];
        *(short8*)&Bs[srow][shalf + 8] = bsrc[1];
        __syncthreads();

        short8 af[4], bfv[4];
#pragma unroll
        for (int i = 0; i < 4; ++i)
            af[i] = *(const short8*)&As[mh + i * 16 + l15][quad * 8];
#pragma unroll
        for (int j = 0; j < 4; ++j)
            bfv[j] = *(const short8*)&Bs[nh + j * 16 + l15][quad * 8];
#pragma unroll
        for (int i = 0; i < 4; ++i)
#pragma unroll
            for (int j = 0; j < 4; ++j)
                acc[i][j] = __builtin_amdgcn_mfma_f32_16x16x32_bf16(af[i], bfv[j], acc[i][j], 0, 0, 0);
        __syncthreads();
    }

    short* Cb;
    int stride, cb;
    if (n0 < 512) { Cb = qall;  stride = 512;  cb = n0; }
    else          { Cb = kvall; stride = 1024; cb = n0 - 512; }

#pragma unroll
    for (int i = 0; i < 4; ++i)
#pragma unroll
        for (int j = 0; j < 4; ++j) {
            const int col = cb + nh + j * 16 + l15;
#pragma unroll
            for (int r = 0; r < 4; ++r) {
                const int row = m0 + mh + i * 16 + quad * 4 + r;
                Cb[(long)row * stride + col] = f2bf(acc[i][j][r]);
            }
        }
}

// ---------------------------------------------------------------------------
// Fused KNN attention, bf16 storage / f32 math (unchanged since round 5).
// ---------------------------------------------------------------------------
__global__ __launch_bounds__(256) void attn_kernel(const short* qall,
                                                   const short* __restrict__ kvall,
                                                   const int* __restrict__ idxp,
                                                   short* outp)
{
    __shared__ float attn_s[4][8][8];
    const int wave = threadIdx.x >> 6;
    const int lane = threadIdx.x & 63;
    const int g = blockIdx.x * 4 + wave;
    const int b = g >> 13;
    const int* myidx = idxp + (long)g * 8;

    {
        const int h = lane >> 3;
        const int k = lane & 7;
        const int j = myidx[k];
        const short8* qrow = (const short8*)(qall + (long)g * 512 + h * 64);
        const short8* krow = (const short8*)(kvall + ((long)(b * N_PTS + j)) * 1024 + h * 64);

        float dot = 0.f;
#pragma unroll
        for (int c = 0; c < 8; ++c) {
            const short8 qv = qrow[c];
            const short8 kv = krow[c];
#pragma unroll
            for (int e = 0; e < 8; ++e)
                dot = fmaf(bf2f(qv[e]), bf2f(kv[e]), dot);
        }
        dot *= 0.125f;

        float m = dot;
#pragma unroll
        for (int off = 1; off < 8; off <<= 1)
            m = fmaxf(m, __shfl_xor(m, off, 8));
        const float e = __expf(dot - m);
        float ssum = e;
#pragma unroll
        for (int off = 1; off < 8; off <<= 1)
            ssum += __shfl_xor(ssum, off, 8);
        attn_s[wave][h][k] = e / ssum;
    }
    __syncthreads();                      // drains q reads before aliased writes

    const int d8 = lane * 8;
    const int h2 = lane >> 3;
    float o[8] = {0.f, 0.f, 0.f, 0.f, 0.f, 0.f, 0.f, 0.f};
#pragma unroll
    for (int kk = 0; kk < 8; ++kk) {
        const int jj = myidx[kk];
        const float w = attn_s[wave][h2][kk];
        const short8 v = *(const short8*)(kvall + ((long)(b * N_PTS + jj)) * 1024 + 512 + d8);
#pragma unroll
        for (int e = 0; e < 8; ++e)
            o[e] = fmaf(w, bf2f(v[e]), o[e]);
    }
    short8 ov = {f2bf(o[0]), f2bf(o[1]), f2bf(o[2]), f2bf(o[3]),
                 f2bf(o[4]), f2bf(o[5]), f2bf(o[6]), f2bf(o[7])};
    *(short8*)(outp + (long)g * 512 + d8) = ov;
}

// ---------------------------------------------------------------------------
// Out-projection bf16 MFMA GEMM: C f32 = A[M,512] x Bt[256,512]^T + bias.
// ---------------------------------------------------------------------------
__global__ __launch_bounds__(256) void gemm_out(const short* __restrict__ A,
                                                const short* __restrict__ Bt,
                                                const float* __restrict__ bias,
                                                float* __restrict__ C,
                                                int N, int Kd)
{
    __shared__ short As[128][40];
    __shared__ short Bs[128][40];

    const int tid  = threadIdx.x;
    const int lane = tid & 63;
    const int wv   = tid >> 6;
    const int quad = lane >> 4;
    const int l15  = lane & 15;
    const int m0 = blockIdx.y * 128;
    const int n0 = blockIdx.x * 128;
    const int mh = (wv & 1) * 64, nh = (wv >> 1) * 64;

    const int srow  = tid >> 1;
    const int shalf = (tid & 1) * 16;

    float4v acc[4][4];
#pragma unroll
    for (int i = 0; i < 4; ++i)
#pragma unroll
        for (int j = 0; j < 4; ++j) acc[i][j] = (float4v)(0.f);

    for (int k0 = 0; k0 < Kd; k0 += 32) {
        const short8* asrc = (const short8*)(A + (long)(m0 + srow) * Kd + k0 + shalf);
        const short8* bsrc = (const short8*)(Bt + (long)(n0 + srow) * Kd + k0 + shalf);
        *(short8*)&As[srow][shalf]     = asrc[0];
        *(short8*)&As[srow][shalf + 8] = asrc[1];
        *(short8*)&Bs[srow][shalf]     = bsrc[0];
        *(short8*)&Bs[srow][shalf + 8] = bsrc[1];
        __syncthreads();

        short8 af[4], bfv[4];
#pragma unroll
        for (int i = 0; i < 4; ++i)
            af[i] = *(const short8*)&As[mh + i * 16 + l15][quad * 8];
#pragma unroll
        for (int j = 0; j < 4; ++j)
            bfv[j] = *(const short8*)&Bs[nh + j * 16 + l15][quad * 8];
#pragma unroll
        for (int i = 0; i < 4; ++i)
#pragma unroll
            for (int j = 0; j < 4; ++j)
                acc[i][j] = __builtin_amdgcn_mfma_f32_16x16x32_bf16(af[i], bfv[j], acc[i][j], 0, 0, 0);
        __syncthreads();
    }

#pragma unroll
    for (int i = 0; i < 4; ++i)
#pragma unroll
        for (int j = 0; j < 4; ++j) {
            const int col = n0 + nh + j * 16 + l15;
            const float bb = bias[col];
#pragma unroll
            for (int r = 0; r < 4; ++r) {
                const int row = m0 + mh + i * 16 + quad * 4 + r;
                C[(long)row * N + col] = acc[i][j][r] + bb;
            }
        }
}

// ---------------------------------------------------------------------------
extern "C" void kernel_launch(void* const* d_in, const int* in_sizes, int n_in,
                              void* d_out, int out_size, void* d_ws, size_t ws_size,
                              hipStream_t stream)
{
    const float* x    = (const float*)d_in[0];  // [2,8192,256]
    const float* pos  = (const float*)d_in[1];  // [2,8192,3]
    const float* Wq   = (const float*)d_in[2];  // [256,512]
    const float* Wkv  = (const float*)d_in[3];  // [256,1024]
    const float* Wout = (const float*)d_in[4];  // [512,256]
    const float* bout = (const float*)d_in[5];  // [256]
    float* out = (float*)d_out;                 // [2,8192,256] f32

    const int M = 16384;

    // workspace layout (partial has its own slice):
    char* ws = (char*)d_ws;
    int*   idxp  = (int*)ws;                          ws += 1 << 19;             // 512 KB
    short* qall  = (short*)ws;                        ws += (long)M * 512 * 2;   // 16 MB
    short* kvall = (short*)ws;                        ws += (long)M * 1024 * 2;  // 32 MB
    short* xb    = (short*)ws;                        ws += (long)M * 256 * 2;   // 8 MB
    short* wqkvt = (short*)ws;                        ws += 1536 * 256 * 2;      // 768 KB
    short* woutt = (short*)ws;                        ws += 256 * 512 * 2;       // 256 KB
    u64*  partial = (u64*)ws;                         ws += (long)128 * 16384 * 8; // 16 MB

    fused_knn_conv<<<5120, 256, 0, stream>>>(pos, partial, x, Wq, Wkv, Wout,
                                             xb, wqkvt, woutt);
    fused_gemm_merge<<<1600, 256, 0, stream>>>(xb, wqkvt, qall, kvall, partial, idxp);
    attn_kernel<<<M / 4, 256, 0, stream>>>(qall, kvall, idxp, qall);   // in-place
    gemm_out<<<dim3(2, 128), 256, 0, stream>>>(qall, woutt, bout, out, 256, 512);
}